// Round 7
// baseline (690.042 us; speedup 1.0000x reference)
//
#include <hip/hip_runtime.h>
#include <hip/hip_bf16.h>

typedef _Float16 h16;
typedef _Float16 f16x8 __attribute__((ext_vector_type(8)));
typedef float f32x16 __attribute__((ext_vector_type(16)));

constexpr int T = 8192, H = 1024, F = 2816, E = 8;
constexpr int NENT = T * 2;
constexpr int SLACK = 128;
constexpr int BM = 256, BK = 64;
constexpr int MT256 = T / BM;       // 32
constexpr int NT1b = F / 128;       // 22  (gemm1 BN=128, x2 matrices)
constexpr int NT2b = H / 256;       // 4   (gemm2 BN=256)
constexpr int NKH = H / BK;         // 16
constexpr int NKF = F / BK;         // 44

#define GLD16(gptr, lptr)                                                        \
  __builtin_amdgcn_global_load_lds(                                              \
      (const __attribute__((address_space(1))) unsigned int*)(gptr),             \
      (__attribute__((address_space(3))) unsigned int*)(lptr), 16, 0, 0)

#define ASM_VMCNT(n) asm volatile("s_waitcnt vmcnt(" #n ")" ::: "memory")
#define SBAR()       __builtin_amdgcn_s_barrier()

// Per-half LDS tile: logical rows x 32 h16 packed as phys [rows/2][64 h16]
// (128 B/phys-row), XOR-swizzled 16B slots. Conflict-free (verified R2-R6).
__device__ __forceinline__ int lds_off(int row, int s) {
  int r2 = row >> 1;
  int p = (((row & 1) << 2) | s) ^ (r2 & 7);
  return r2 * 128 + p * 16;
}
__device__ __forceinline__ void inv_rowcol(int c, int i, int& row, int& col) {
  int r2 = c * 8 + (i >> 3);
  int slot8 = (i & 7) ^ (r2 & 7);
  row = r2 * 2 + (slot8 >> 2);
  col = (slot8 & 3) * 8;
}

// ---------------- routing ----------------
__global__ void k_routing(const float* __restrict__ logits,
                          int* __restrict__ top_i, float* __restrict__ top_w,
                          int* __restrict__ counts) {
  int t = blockIdx.x * blockDim.x + threadIdx.x;
  if (t >= T) return;
  float l[E];
#pragma unroll
  for (int j = 0; j < E; ++j) l[j] = logits[t * E + j];
  int i1 = 0; float v1 = l[0];
#pragma unroll
  for (int j = 1; j < E; ++j) if (l[j] > v1) { v1 = l[j]; i1 = j; }
  int i2 = -1; float v2 = -3.4e38f;
#pragma unroll
  for (int j = 0; j < E; ++j) if (j != i1 && l[j] > v2) { v2 = l[j]; i2 = j; }
  float e2 = __expf(v2 - v1);
  float inv = 1.0f / (1.0f + e2);
  top_i[2 * t] = i1; top_i[2 * t + 1] = i2;
  top_w[2 * t] = inv; top_w[2 * t + 1] = e2 * inv;
  atomicAdd(&counts[i1], 1);
  atomicAdd(&counts[i2], 1);
}

__global__ void k_init_counts(int* counts) {
  if (threadIdx.x < E) counts[threadIdx.x] = 0;
}

__global__ void k_prefix(const int* __restrict__ counts, int* __restrict__ offs,
                         int* __restrict__ fill) {
  if (threadIdx.x == 0) {
    int s = 0;
    for (int e = 0; e < E; ++e) { offs[e] = s; s += counts[e]; fill[e] = 0; }
  }
}

__global__ void k_scatter(const int* __restrict__ top_i, const float* __restrict__ top_w,
                          const int* __restrict__ offs, int* __restrict__ fill,
                          int* __restrict__ etok, float* __restrict__ ew,
                          int* __restrict__ tok2ent) {
  int t = blockIdx.x * blockDim.x + threadIdx.x;
  if (t >= T) return;
#pragma unroll
  for (int k = 0; k < 2; ++k) {
    int e = top_i[2 * t + k];
    int pos = atomicAdd(&fill[e], 1);
    int idx = offs[e] + pos;
    etok[idx] = t;
    ew[idx] = top_w[2 * t + k];
    tok2ent[2 * t + k] = idx;
  }
}

// ---------------- fp32 -> fp16 ----------------
__global__ void k_cvt(const float* __restrict__ s, h16* __restrict__ d) {
  size_t i = (size_t)(blockIdx.x * blockDim.x + threadIdx.x) * 8;
  float4 a = *(const float4*)(s + i);
  float4 b = *(const float4*)(s + i + 4);
  f16x8 h = {(h16)a.x, (h16)a.y, (h16)a.z, (h16)a.w,
             (h16)b.x, (h16)b.y, (h16)b.z, (h16)b.w};
  *(f16x8*)(d + i) = h;
}

// ---------------- combine: out[t] = w0*y[p0] + w1*y[p1] ----------------
__global__ void k_combine(const h16* __restrict__ y, const int* __restrict__ tok2ent,
                          const float* __restrict__ topw, float* __restrict__ out) {
  int i = blockIdx.x * blockDim.x + threadIdx.x;
  int t = i >> 7;
  int h0 = (i & 127) << 3;
  int p0 = tok2ent[2 * t], p1 = tok2ent[2 * t + 1];
  float w0 = topw[2 * t], w1 = topw[2 * t + 1];
  f16x8 y0 = *(const f16x8*)(y + (size_t)p0 * H + h0);
  f16x8 y1 = *(const f16x8*)(y + (size_t)p1 * H + h0);
  float4 o0, o1;
  o0.x = w0 * (float)y0[0] + w1 * (float)y1[0];
  o0.y = w0 * (float)y0[1] + w1 * (float)y1[1];
  o0.z = w0 * (float)y0[2] + w1 * (float)y1[2];
  o0.w = w0 * (float)y0[3] + w1 * (float)y1[3];
  o1.x = w0 * (float)y0[4] + w1 * (float)y1[4];
  o1.y = w0 * (float)y0[5] + w1 * (float)y1[5];
  o1.z = w0 * (float)y0[6] + w1 * (float)y1[6];
  o1.w = w0 * (float)y0[7] + w1 * (float)y1[7];
  *(float4*)(out + (size_t)t * H + h0) = o0;
  *(float4*)(out + (size_t)t * H + h0 + 4) = o1;
}

// ---------------- GEMM1: 256x(128x2), 4-phase/K-tile, 32x32x16 MFMA ----------------
// LDS per dbuf (64KB): A-kh0 16K | A-kh1 16K | B1-kh0 8K | B1-kh1 8K | B3-kh0 8K | B3-kh1 8K
__launch_bounds__(512, 2)
__global__ void k_gemm1(const h16* __restrict__ x16,
                        const h16* __restrict__ w1h, const h16* __restrict__ w3h,
                        const int* __restrict__ counts, const int* __restrict__ offs,
                        const int* __restrict__ etok, h16* __restrict__ act) {
  constexpr int NWG = E * MT256 * NT1b;              // 5632, %8==0
  int orig = blockIdx.x;
  int bid = (orig & 7) * (NWG / 8) + (orig >> 3);
  int e  = bid / (MT256 * NT1b);
  int r  = bid % (MT256 * NT1b);
  int nt = r / MT256;
  int mt = r % MT256;
  int n_e = counts[e];
  if (mt * BM >= n_e) return;
  int base = offs[e];

  __shared__ char lds[131072];

  int tid = threadIdx.x;
  int lane = tid & 63, wid = tid >> 6;
  int wm = (wid >> 2) * 128;          // 2 M-groups (128 rows each)
  int wn = (wid & 3) * 32;            // 4 N-groups (32 cols each)
  int l31 = lane & 31;
  int hi  = lane >> 5;                // k-half selector within 16-k step

  auto Ab  = [&](int d, int h) -> char* { return lds + d * 65536 + h * 16384; };
  auto B1b = [&](int d, int h) -> char* { return lds + d * 65536 + 32768 + h * 8192; };
  auto B3b = [&](int d, int h) -> char* { return lds + d * 65536 + 49152 + h * 8192; };

  const h16* gA[2];
#pragma unroll
  for (int j = 0; j < 2; ++j) {
    int row, col;
    inv_rowcol(2 * wid + j, lane, row, col);
    int gr = mt * BM + row; if (gr >= n_e) gr = n_e - 1;
    gA[j] = x16 + (size_t)etok[base + gr] * H + col;
  }
  const h16 *gB1, *gB3;
  {
    int row, col;
    inv_rowcol(wid, lane, row, col);
    size_t w = ((size_t)e * F + (size_t)nt * 128 + row) * H + col;
    gB1 = w1h + w;
    gB3 = w3h + w;
  }

  auto stA = [&](int d, int h, int kt) {
#pragma unroll
    for (int j = 0; j < 2; ++j)
      GLD16(gA[j] + kt * 64 + h * 32, Ab(d, h) + (2 * wid + j) * 1024);
  };
  auto stB = [&](int d, int h, int kt) {
    GLD16(gB1 + kt * 64 + h * 32, B1b(d, h) + wid * 1024);
    GLD16(gB3 + kt * 64 + h * 32, B3b(d, h) + wid * 1024);
  };

  // frag offsets (within a 32-k half-region): kq = k-quarter (16-k step) in half
  int aoff[4][2], boff[2];
#pragma unroll
  for (int mi = 0; mi < 4; ++mi)
#pragma unroll
    for (int kq = 0; kq < 2; ++kq)
      aoff[mi][kq] = lds_off(wm + mi * 32 + l31, kq * 2 + hi);
#pragma unroll
  for (int kq = 0; kq < 2; ++kq)
    boff[kq] = lds_off(wn + l31, kq * 2 + hi);

  f32x16 ag[4] = {{0.f}, {0.f}, {0.f}, {0.f}};
  f32x16 au[4] = {{0.f}, {0.f}, {0.f}, {0.f}};

#define G1_MFMA(MI0, AF, B1F, B3F)                                               \
  __builtin_amdgcn_s_setprio(1);                                                 \
  _Pragma("unroll") for (int m = 0; m < 2; ++m)                                  \
  _Pragma("unroll") for (int kq = 0; kq < 2; ++kq) {                             \
    ag[MI0 + m] = __builtin_amdgcn_mfma_f32_32x32x16_f16(AF[m][kq], B1F[kq], ag[MI0 + m], 0, 0, 0); \
    au[MI0 + m] = __builtin_amdgcn_mfma_f32_32x32x16_f16(AF[m][kq], B3F[kq], au[MI0 + m], 0, 0, 0); \
  }                                                                              \
  __builtin_amdgcn_s_setprio(0);

  // prologue: tile0 fully (8 ops), tile1 all but A-kh1 (6 ops)
  stA(0, 0, 0); stB(0, 0, 0); stB(0, 1, 0); stA(0, 1, 0);
  stB(1, 0, 1); stB(1, 1, 1); stA(1, 0, 1);
  ASM_VMCNT(6);
  SBAR();

  for (int t = 0; t < NKH; ++t) {
    int cur = t & 1;
    // ph0: A[m0-1] kh0 + B kh0; stage A-kh1(t+1) -> other dbuf
    f16x8 aL0[2][2], b1k0[2], b3k0[2];
#pragma unroll
    for (int m = 0; m < 2; ++m)
#pragma unroll
      for (int kq = 0; kq < 2; ++kq)
        aL0[m][kq] = *(const f16x8*)(Ab(cur, 0) + aoff[m][kq]);
#pragma unroll
    for (int kq = 0; kq < 2; ++kq) {
      b1k0[kq] = *(const f16x8*)(B1b(cur, 0) + boff[kq]);
      b3k0[kq] = *(const f16x8*)(B3b(cur, 0) + boff[kq]);
    }
    if (t + 1 < NKH) stA(cur ^ 1, 1, t + 1);
    SBAR();
    G1_MFMA(0, aL0, b1k0, b3k0)
    SBAR();
    // ph1: A[m0-1] kh1 + B kh1; stage B-kh0(t+2) -> cur
    f16x8 aL1[2][2], b1k1[2], b3k1[2];
#pragma unroll
    for (int m = 0; m < 2; ++m)
#pragma unroll
      for (int kq = 0; kq < 2; ++kq)
        aL1[m][kq] = *(const f16x8*)(Ab(cur, 1) + aoff[m][kq]);
#pragma unroll
    for (int kq = 0; kq < 2; ++kq) {
      b1k1[kq] = *(const f16x8*)(B1b(cur, 1) + boff[kq]);
      b3k1[kq] = *(const f16x8*)(B3b(cur, 1) + boff[kq]);
    }
    if (t + 2 < NKH) stB(cur, 0, t + 2);
    SBAR();
    G1_MFMA(0, aL1, b1k1, b3k1)
    SBAR();
    // ph2: A[m2-3] kh0 (B cached); stage B-kh1(t+2) -> cur
    f16x8 aH0[2][2];
#pragma unroll
    for (int m = 0; m < 2; ++m)
#pragma unroll
      for (int kq = 0; kq < 2; ++kq)
        aH0[m][kq] = *(const f16x8*)(Ab(cur, 0) + aoff[2 + m][kq]);
    if (t + 2 < NKH) stB(cur, 1, t + 2);
    SBAR();
    G1_MFMA(2, aH0, b1k0, b3k0)
    SBAR();
    // ph3: A[m2-3] kh1; stage A-kh0(t+2) -> cur; counted vmcnt
    f16x8 aH1[2][2];
#pragma unroll
    for (int m = 0; m < 2; ++m)
#pragma unroll
      for (int kq = 0; kq < 2; ++kq)
        aH1[m][kq] = *(const f16x8*)(Ab(cur, 1) + aoff[2 + m][kq]);
    if (t + 2 < NKH) stA(cur, 0, t + 2);
    SBAR();
    G1_MFMA(2, aH1, b1k1, b3k1)
    if (t + 2 < NKH) { ASM_VMCNT(6); } else { ASM_VMCNT(0); }
    SBAR();
  }
#undef G1_MFMA

  // epilogue: silu(g)*u -> act fp16
  // 32x32 C layout: col = lane&31, row = (reg&3) + 8*(reg>>2) + 4*(lane>>5)
#pragma unroll
  for (int mi = 0; mi < 4; ++mi) {
#pragma unroll
    for (int rg = 0; rg < 16; ++rg) {
      int row = (rg & 3) + 8 * (rg >> 2) + 4 * hi;
      int grow = mt * BM + wm + mi * 32 + row;
      if (grow < n_e) {
        float g = ag[mi][rg];
        float u = au[mi][rg];
        float s = g / (1.0f + __expf(-g)) * u;
        act[(size_t)(base + grow) * F + (size_t)nt * 128 + wn + l31] = (h16)s;
      }
    }
  }
}

// ---------------- GEMM2: 256x256, 4-phase/K-tile, 32x32x16 MFMA ----------------
// LDS per dbuf (64KB): A-kh0 16K | A-kh1 16K | B-kh0 16K | B-kh1 16K
__launch_bounds__(512, 2)
__global__ void k_gemm2(const h16* __restrict__ act, const h16* __restrict__ w2h,
                        const int* __restrict__ counts, const int* __restrict__ offs,
                        h16* __restrict__ y16) {
  constexpr int NWG = E * MT256 * NT2b;              // 1024, %8==0
  int orig = blockIdx.x;
  int bid = (orig & 7) * (NWG / 8) + (orig >> 3);
  int e  = bid / (MT256 * NT2b);
  int r  = bid % (MT256 * NT2b);
  int nt = r / MT256;
  int mt = r % MT256;
  int n_e = counts[e];
  if (mt * BM >= n_e) return;
  int base = offs[e];

  __shared__ char lds[131072];

  int tid = threadIdx.x;
  int lane = tid & 63, wid = tid >> 6;
  int wm = (wid >> 2) * 128;
  int wn = (wid & 3) * 64;            // 2 n-blocks of 32
  int l31 = lane & 31;
  int hi  = lane >> 5;

  auto Ab = [&](int d, int h) -> char* { return lds + d * 65536 + h * 16384; };
  auto Bb = [&](int d, int h) -> char* { return lds + d * 65536 + 32768 + h * 16384; };

  const h16* gA[2]; const h16* gB[2];
#pragma unroll
  for (int j = 0; j < 2; ++j) {
    int row, col;
    inv_rowcol(2 * wid + j, lane, row, col);
    int gr = mt * BM + row; if (gr >= n_e) gr = n_e - 1;
    gA[j] = act + (size_t)(base + gr) * F + col;
    gB[j] = w2h + ((size_t)e * H + (size_t)nt * 256 + row) * F + col;
  }

  auto stA = [&](int d, int h, int kt) {
#pragma unroll
    for (int j = 0; j < 2; ++j)
      GLD16(gA[j] + kt * 64 + h * 32, Ab(d, h) + (2 * wid + j) * 1024);
  };
  auto stB = [&](int d, int h, int kt) {
#pragma unroll
    for (int j = 0; j < 2; ++j)
      GLD16(gB[j] + kt * 64 + h * 32, Bb(d, h) + (2 * wid + j) * 1024);
  };

  int aoff[4][2], boff[2][2];
#pragma unroll
  for (int mi = 0; mi < 4; ++mi)
#pragma unroll
    for (int kq = 0; kq < 2; ++kq)
      aoff[mi][kq] = lds_off(wm + mi * 32 + l31, kq * 2 + hi);
#pragma unroll
  for (int nj = 0; nj < 2; ++nj)
#pragma unroll
    for (int kq = 0; kq < 2; ++kq)
      boff[nj][kq] = lds_off(wn + nj * 32 + l31, kq * 2 + hi);

  f32x16 acc[4][2] = {{{0.f},{0.f}},{{0.f},{0.f}},{{0.f},{0.f}},{{0.f},{0.f}}};

#define G2_MFMA(MI0, AF, BF)                                                     \
  __builtin_amdgcn_s_setprio(1);                                                 \
  _Pragma("unroll") for (int m = 0; m < 2; ++m)                                  \
  _Pragma("unroll") for (int nj = 0; nj < 2; ++nj)                               \
  _Pragma("unroll") for (int kq = 0; kq < 2; ++kq) {                             \
    acc[MI0 + m][nj] = __builtin_amdgcn_mfma_f32_32x32x16_f16(AF[m][kq], BF[nj][kq], acc[MI0 + m][nj], 0, 0, 0); \
  }                                                                              \
  __builtin_amdgcn_s_setprio(0);

  stA(0, 0, 0); stB(0, 0, 0); stB(0, 1, 0); stA(0, 1, 0);
  stB(1, 0, 1); stB(1, 1, 1); stA(1, 0, 1);
  ASM_VMCNT(6);
  SBAR();

  for (int t = 0; t < NKF; ++t) {
    int cur = t & 1;
    // ph0
    f16x8 aL0[2][2], bk0[2][2];
#pragma unroll
    for (int m = 0; m < 2; ++m)
#pragma unroll
      for (int kq = 0; kq < 2; ++kq)
        aL0[m][kq] = *(const f16x8*)(Ab(cur, 0) + aoff[m][kq]);
#pragma unroll
    for (int nj = 0; nj < 2; ++nj)
#pragma unroll
      for (int kq = 0; kq < 2; ++kq)
        bk0[nj][kq] = *(const f16x8*)(Bb(cur, 0) + boff[nj][kq]);
    if (t + 1 < NKF) stA(cur ^ 1, 1, t + 1);
    SBAR();
    G2_MFMA(0, aL0, bk0)
    SBAR();
    // ph1
    f16x8 aL1[2][2], bk1[2][2];
#pragma unroll
    for (int m = 0; m < 2; ++m)
#pragma unroll
      for (int kq = 0; kq < 2; ++kq)
        aL1[m][kq] = *(const f16x8*)(Ab(cur, 1) + aoff[m][kq]);
#pragma unroll
    for (int nj = 0; nj < 2; ++nj)
#pragma unroll
      for (int kq = 0; kq < 2; ++kq)
        bk1[nj][kq] = *(const f16x8*)(Bb(cur, 1) + boff[nj][kq]);
    if (t + 2 < NKF) stB(cur, 0, t + 2);
    SBAR();
    G2_MFMA(0, aL1, bk1)
    SBAR();
    // ph2
    f16x8 aH0[2][2];
#pragma unroll
    for (int m = 0; m < 2; ++m)
#pragma unroll
      for (int kq = 0; kq < 2; ++kq)
        aH0[m][kq] = *(const f16x8*)(Ab(cur, 0) + aoff[2 + m][kq]);
    if (t + 2 < NKF) stB(cur, 1, t + 2);
    SBAR();
    G2_MFMA(2, aH0, bk0)
    SBAR();
    // ph3
    f16x8 aH1[2][2];
#pragma unroll
    for (int m = 0; m < 2; ++m)
#pragma unroll
      for (int kq = 0; kq < 2; ++kq)
        aH1[m][kq] = *(const f16x8*)(Ab(cur, 1) + aoff[2 + m][kq]);
    if (t + 2 < NKF) stA(cur, 0, t + 2);
    SBAR();
    G2_MFMA(2, aH1, bk1)
    if (t + 2 < NKF) { ASM_VMCNT(6); } else { ASM_VMCNT(0); }
    SBAR();
  }
#undef G2_MFMA

#pragma unroll
  for (int mi = 0; mi < 4; ++mi) {
#pragma unroll
    for (int rg = 0; rg < 16; ++rg) {
      int row = (rg & 3) + 8 * (rg >> 2) + 4 * hi;
      int grow = mt * BM + wm + mi * 32 + row;
      if (grow < n_e) {
        h16* yrow = y16 + (size_t)(base + grow) * H + (size_t)nt * 256 + wn;
#pragma unroll
        for (int nj = 0; nj < 2; ++nj)
          yrow[nj * 32 + l31] = (h16)acc[mi][nj][rg];
      }
    }
  }
}

extern "C" void kernel_launch(void* const* d_in, const int* in_sizes, int n_in,
                              void* d_out, int out_size, void* d_ws, size_t ws_size,
                              hipStream_t stream) {
  const float* x  = (const float*)d_in[0];
  const float* rl = (const float*)d_in[1];
  const float* w1 = (const float*)d_in[2];
  const float* w3 = (const float*)d_in[3];
  const float* w2 = (const float*)d_in[4];
  float* out = (float*)d_out;

  char* ws = (char*)d_ws;
  size_t off = 0;
  auto alloc = [&](size_t bytes) -> void* {
    void* p = ws + off;
    off = (off + bytes + 255) & ~(size_t)255;
    return p;
  };
  h16*   x16  = (h16*)  alloc((size_t)T * H * sizeof(h16));
  h16*   act  = (h16*)  alloc((size_t)(NENT + SLACK) * F * sizeof(h16));
  int*   etok = (int*)  alloc((size_t)(NENT + SLACK) * sizeof(int));
  float* ew   = (float*)alloc((size_t)(NENT + SLACK) * sizeof(float));
  int*   topi = (int*)  alloc((size_t)NENT * sizeof(int));
  float* topw = (float*)alloc((size_t)NENT * sizeof(float));
  int* tok2ent = (int*) alloc((size_t)NENT * sizeof(int));
  int* counts = (int*)  alloc(64);
  int* offs   = (int*)  alloc(64);
  int* fill   = (int*)  alloc(64);
  h16* w1h = (h16*)alloc((size_t)E * F * H * sizeof(h16));
  h16* w3h = (h16*)alloc((size_t)E * F * H * sizeof(h16));
  h16* w2h = (h16*)alloc((size_t)E * H * F * sizeof(h16));
  h16* y16 = (h16*)alloc((size_t)(NENT + SLACK) * H * sizeof(h16));
  (void)in_sizes; (void)n_in; (void)ws_size;

  k_init_counts<<<1, 64, 0, stream>>>(counts);
  k_routing<<<(T + 255) / 256, 256, 0, stream>>>(rl, topi, topw, counts);
  k_prefix<<<1, 64, 0, stream>>>(counts, offs, fill);
  k_scatter<<<(T + 255) / 256, 256, 0, stream>>>(topi, topw, offs, fill, etok, ew, tok2ent);
  k_cvt<<<(T * H / 8) / 256, 256, 0, stream>>>(x, x16);
  constexpr int WG = (E * F * H / 8) / 256;  // 11264
  k_cvt<<<WG, 256, 0, stream>>>(w1, w1h);
  k_cvt<<<WG, 256, 0, stream>>>(w3, w3h);
  k_cvt<<<WG, 256, 0, stream>>>(w2, w2h);
  k_gemm1<<<E * MT256 * NT1b, 512, 0, stream>>>(x16, w1h, w3h, counts, offs, etok, act);
  k_gemm2<<<E * MT256 * NT2b, 512, 0, stream>>>(act, w2h, counts, offs, y16);
  k_combine<<<(T * H / 8) / 256, 256, 0, stream>>>(y16, tok2ent, topw, out);
}